// Round 5
// baseline (619.595 us; speedup 1.0000x reference)
//
#include <hip/hip_runtime.h>
#include <math.h>

#define NN 50000
#define EE 800000
#define NPAD 50048           // 391 * 128
#define PC 768               // packed GEMM column count
// GEMM col map: [0,128) Q -> Pq fp32 | [128,384) K/V -> KVb bf16 |
//               [384,512) SKIP, [512,640) RES, [640,704) WEQ, 704 GATE -> Pe bf16
// Pe row (384 ushorts): [0,128) skip | [128,256) res | [256,320) weq | 320 gate
// KVb[node] = 128 dwords, INTERLEAVED: dword 2c   = (bf16 K[c] lo, bf16 K[c+64] hi)
//                                      dword 2c+1 = (bf16 V[c] lo, bf16 V[c+64] hi)

typedef short bf16x8 __attribute__((ext_vector_type(8)));
typedef float f32x4 __attribute__((ext_vector_type(4)));

#define ASCALE 0.08838834764831845f   // 1/sqrt(128)

__device__ inline unsigned short f2bf(float f)
{
    unsigned u = __float_as_uint(f);
    u = u + 0x7fff + ((u >> 16) & 1);   // RNE
    return (unsigned short)(u >> 16);
}

__device__ inline float bfu(unsigned short us)
{
    return __uint_as_float((unsigned)us << 16);
}

// ---------------------------------------------------------------------------
// K0: weight prep  wqe[r][m] = sum_c Wq[r][c] * We[m][c]   ([128,64])
// ---------------------------------------------------------------------------
__global__ __launch_bounds__(256) void k_wprep(const float* __restrict__ Wq,
                                               const float* __restrict__ bq,
                                               const float* __restrict__ We,
                                               float* __restrict__ wqe,
                                               float* __restrict__ bqe)
{
    int idx = blockIdx.x * 256 + threadIdx.x;
    if (idx < 8192) {
        int r = idx >> 6, m = idx & 63;
        float acc = 0.f;
        for (int c = 0; c < 128; ++c) acc += Wq[r * 128 + c] * We[m * 128 + c];
        wqe[r * 64 + m] = acc;
    } else if (idx < 8256) {
        int m = idx - 8192;
        float acc = 0.f;
        for (int c = 0; c < 128; ++c) acc += bq[c] * We[m * 128 + c];
        bqe[m] = acc;
    }
}

// ---------------------------------------------------------------------------
// K1a: pack x -> bf16 [NPAD][128], zero pad rows
// ---------------------------------------------------------------------------
__global__ __launch_bounds__(256) void k_packx(const float* __restrict__ x,
                                               short* __restrict__ Xb)
{
    int t = blockIdx.x * 256 + threadIdx.x;
    int base = t * 4;
    if (base >= NPAD * 128) return;
    short s0 = 0, s1 = 0, s2 = 0, s3 = 0;
    if (base < NN * 128) {
        const float4 v = *(const float4*)(x + base);
        s0 = f2bf(v.x); s1 = f2bf(v.y); s2 = f2bf(v.z); s3 = f2bf(v.w);
    }
    short4 o; o.x = s0; o.y = s1; o.z = s2; o.w = s3;
    *(short4*)(Xb + base) = o;
}

// ---------------------------------------------------------------------------
// K1b: pack transposed weight WT[col][k] (bf16 [768][128]) + bias[768]
//      + WeTb[c][kk] (bf16 [128][72], row-padded, zeros in pad)
// ---------------------------------------------------------------------------
__global__ __launch_bounds__(256) void k_packw(
    const float* __restrict__ Wq, const float* __restrict__ bq,
    const float* __restrict__ Wk, const float* __restrict__ bk,
    const float* __restrict__ Wv, const float* __restrict__ bv,
    const float* __restrict__ Wskip, const float* __restrict__ bskip,
    const float* __restrict__ Wres, const float* __restrict__ bres,
    const float* __restrict__ Wgate, const float* __restrict__ bgate,
    const float* __restrict__ wqe, const float* __restrict__ bqe,
    const float* __restrict__ We,
    short* __restrict__ WT, float* __restrict__ bias,
    unsigned short* __restrict__ WeTb)
{
    int idx = blockIdx.x * 256 + threadIdx.x;
    if (idx < PC * 128) {
        int col = idx >> 7, k = idx & 127;
        float v;
        if (col < 128)      v = Wq[k * 128 + col];
        else if (col < 256) v = Wk[k * 128 + (col - 128)];
        else if (col < 384) v = Wv[k * 128 + (col - 256)];
        else if (col < 512) v = Wskip[k * 128 + (col - 384)];
        else if (col < 640) v = Wres[k * 128 + (col - 512)];
        else if (col < 704) v = wqe[k * 64 + (col - 640)];
        else if (col == 704) v = Wgate[k];
        else                v = 0.f;
        WT[col * 128 + k] = (short)f2bf(v);
    } else if (idx < PC * 128 + PC) {
        int col = idx - PC * 128;
        float b;
        if (col < 128)      b = bq[col];
        else if (col < 256) b = bk[col - 128];
        else if (col < 384) b = bv[col - 256];
        else if (col < 512) b = bskip[col - 384];
        else if (col < 640) b = bres[col - 512];
        else if (col < 704) b = bqe[col - 640];
        else if (col == 704) b = bgate[0];
        else                b = 0.f;
        bias[col] = b;
    } else if (idx < PC * 128 + PC + 128 * 72) {
        int i2 = idx - (PC * 128 + PC);
        int c = i2 / 72, kk = i2 % 72;
        WeTb[i2] = (kk < 64) ? f2bf(We[kk * 128 + c]) : (unsigned short)0;
    }
}

// ---------------------------------------------------------------------------
// K2: MFMA GEMM. Block tile 128x64, grid (bn fastest) for A-tile L2 reuse.
// bn 0-1 -> Pq fp32; bn 2-5 -> KVb bf16 (interleaved); bn 6-11 -> Pe bf16.
// ---------------------------------------------------------------------------
#define LROW 136
__global__ __launch_bounds__(256) void k_gemm(const short* __restrict__ Xb,
                                              const short* __restrict__ WT,
                                              const float* __restrict__ bias,
                                              float* __restrict__ Pq,
                                              unsigned short* __restrict__ Pe,
                                              unsigned short* __restrict__ KVb16)
{
    __shared__ short Al[128 * LROW];
    __shared__ short Bl[64 * LROW];

    int bn = blockIdx.x;          // 12 col tiles (fastest -> A reuse in L2)
    int bm = blockIdx.y;          // 391 row tiles
    int tid = threadIdx.x;

    const short* gA = Xb + (size_t)bm * 128 * 128;
    const short* gB = WT + (size_t)bn * 64 * 128;

#pragma unroll
    for (int it = 0; it < 8; ++it) {
        int g = it * 256 + tid;           // unit = 8 shorts (16 B)
        int row = g >> 4, c8 = g & 15;
        *(bf16x8*)&Al[row * LROW + c8 * 8] = *(const bf16x8*)(gA + g * 8);
    }
#pragma unroll
    for (int it = 0; it < 4; ++it) {
        int g = it * 256 + tid;
        int row = g >> 4, c8 = g & 15;
        *(bf16x8*)&Bl[row * LROW + c8 * 8] = *(const bf16x8*)(gB + g * 8);
    }
    __syncthreads();

    int wave = tid >> 6, lane = tid & 63;
    int quad = lane >> 4, l16 = lane & 15;
    int r0 = wave * 32;

    f32x4 acc[2][4] = {};
#pragma unroll
    for (int ks = 0; ks < 4; ++ks) {
        int k0 = ks * 32 + quad * 8;
        bf16x8 af0 = *(const bf16x8*)&Al[(r0 + l16) * LROW + k0];
        bf16x8 af1 = *(const bf16x8*)&Al[(r0 + 16 + l16) * LROW + k0];
#pragma unroll
        for (int cn = 0; cn < 4; ++cn) {
            bf16x8 bfr = *(const bf16x8*)&Bl[(cn * 16 + l16) * LROW + k0];
            acc[0][cn] = __builtin_amdgcn_mfma_f32_16x16x32_bf16(af0, bfr, acc[0][cn], 0, 0, 0);
            acc[1][cn] = __builtin_amdgcn_mfma_f32_16x16x32_bf16(af1, bfr, acc[1][cn], 0, 0, 0);
        }
    }

    bool isKV = (bn >= 2 && bn <= 5);
#pragma unroll
    for (int half = 0; half < 2; ++half) {
        int growb = bm * 128 + r0 + half * 16 + quad * 4;
#pragma unroll
        for (int cn = 0; cn < 4; ++cn) {
            int gcol = bn * 64 + cn * 16 + l16;
            float b = bias[gcol];
#pragma unroll
            for (int i = 0; i < 4; ++i) {
                int grow = growb + i;
                if (grow < NN) {
                    float v = acc[half][cn][i] + b;
                    if (bn < 2) {
                        Pq[(size_t)grow * 128 + gcol] = v;
                    } else if (isKV) {
                        // interleaved: K col c -> ushort 4c/4c+1, V col c -> 4c+2/4c+3
                        int c, sub;
                        if (gcol < 192)      { c = gcol - 128; sub = 0; }
                        else if (gcol < 256) { c = gcol - 192; sub = 1; }
                        else if (gcol < 320) { c = gcol - 256; sub = 2; }
                        else                 { c = gcol - 320; sub = 3; }
                        KVb16[(size_t)grow * 256 + c * 4 + sub] = f2bf(v);
                    } else if (gcol <= 704) {
                        if (gcol == 704) v = 1.f / (1.f + __expf(-v));
                        Pe[(size_t)grow * 384 + (gcol - 384)] = f2bf(v);
                    }
                }
            }
        }
    }
}

// ---------------------------------------------------------------------------
// CSR build
// ---------------------------------------------------------------------------
__global__ __launch_bounds__(256) void k_hist(const int* __restrict__ ei,
                                              int* __restrict__ deg, int E)
{
    int e = blockIdx.x * 256 + threadIdx.x;
    if (e < E) atomicAdd(&deg[ei[E + e]], 1);
}

__global__ __launch_bounds__(256) void k_scan1(const int* __restrict__ deg,
                                               int* __restrict__ rs,
                                               int* __restrict__ cs, int n)
{
    __shared__ int sh[256];
    int base = blockIdx.x * 1024;
    int t = threadIdx.x;
    int idx = base + t * 4;
    int v[4];
#pragma unroll
    for (int k = 0; k < 4; ++k) v[k] = (idx + k < n) ? deg[idx + k] : 0;
    int sum = v[0] + v[1] + v[2] + v[3];
    sh[t] = sum;
    __syncthreads();
    for (int off = 1; off < 256; off <<= 1) {
        int add = (t >= off) ? sh[t - off] : 0;
        __syncthreads();
        sh[t] += add;
        __syncthreads();
    }
    int run = sh[t] - sum;
    if (t == 255) cs[blockIdx.x] = sh[255];
#pragma unroll
    for (int k = 0; k < 4; ++k) {
        if (idx + k < n) rs[idx + k] = run;
        run += v[k];
    }
}

__global__ void k_scan2(int* __restrict__ cs, int nc)
{
    __shared__ int sh[64];
    int t = threadIdx.x;
    sh[t] = (t < nc) ? cs[t] : 0;
    __syncthreads();
    if (t == 0) {
        int acc = 0;
        for (int i = 0; i < nc; ++i) { int v = sh[i]; sh[i] = acc; acc += v; }
    }
    __syncthreads();
    if (t < nc) cs[t] = sh[t];
}

__global__ __launch_bounds__(256) void k_scan3(int* __restrict__ rs,
                                               const int* __restrict__ cs,
                                               int* __restrict__ cur, int n, int E)
{
    int i = blockIdx.x * 256 + threadIdx.x;
    if (i < n) {
        int v = rs[i] + cs[i >> 10];
        rs[i] = v;
        cur[i] = v;
    } else if (i == n) {
        rs[n] = E;
    }
}

__global__ __launch_bounds__(256) void k_scatter(const int* __restrict__ ei,
                                                 int* __restrict__ cur,
                                                 int2* __restrict__ sj, int E)
{
    int e = blockIdx.x * 256 + threadIdx.x;
    if (e < E) {
        int d = ei[E + e];
        int pos = atomicAdd(&cur[d], 1);
        int2 v; v.x = ei[e]; v.y = e;
        sj[pos] = v;
    }
}

// ---------------------------------------------------------------------------
// K3: fused attention + epilogue. One wave per node, 4 nodes/block.
// Gather: software-pipelined 8-edge batches (register double-buffer: issue
// batch b+1's sj/KV/ea loads BEFORE the butterfly/exp of batch b, so ~8
// gathers stay in flight through the compute phase). Interleaved bf16 KV
// (1 dwordx2/edge) + fp32 ea (nontemporal).
// Epilogue: cooperative S@We (R2 form — measured best): 4 waves share the
// MFMA work (2 col-tiles each), 1 barrier. Per-wave 16-MFMA variant was
// +33us (R4): serial vmcnt round-trips on B-fragments at low VGPR budget.
// ---------------------------------------------------------------------------
__global__ __launch_bounds__(256) void k_attn_fused(
    const float* __restrict__ Pq, const unsigned short* __restrict__ Pe,
    const unsigned int* __restrict__ KVb,
    const float* __restrict__ ea, const unsigned short* __restrict__ WeTb,
    const int* __restrict__ rs, const int2* __restrict__ sj,
    const float* __restrict__ ln_g, const float* __restrict__ ln_b,
    float* __restrict__ out)
{
    __shared__ unsigned short Sb_l[4 * 64];      // [node][k] bf16
    __shared__ float att_l[4 * 128];             // S@We result

    int tid = threadIdx.x;
    int wave = tid >> 6, lane = tid & 63;
    int node = blockIdx.x * 4 + wave;            // grid is exactly NN/4

    const float* Qrow = Pq + (size_t)node * 128;
    const unsigned short* Erow = Pe + (size_t)node * 384;
    float q0 = Qrow[lane];
    float q1 = Qrow[64 + lane];
    float wq = bfu(Erow[256 + lane]);

    float accd = 0.f, t0 = 0.f, t1 = 0.f, sA = 0.f;
    int beg = rs[node], end = rs[node + 1];

    int nb = (end - beg) >> 3;      // full 8-edge batches
    int p = beg;

    uint2 kv[8]; float av[8];
    if (nb > 0) {
#pragma unroll
        for (int u = 0; u < 8; ++u) {
            long long sv = __builtin_nontemporal_load((const long long*)(sj + p + u));
            int sx = (int)sv, sy = (int)(sv >> 32);
            kv[u] = *(const uint2*)(KVb + (size_t)sx * 128 + 2 * lane);
            av[u] = __builtin_nontemporal_load(ea + (size_t)sy * 64 + lane);
        }
    }
    for (int b = 0; b < nb; ++b) {
        uint2 kvn[8]; float avn[8];
        int np = p + 8;
        if (b + 1 < nb) {           // prefetch next batch before computing
#pragma unroll
            for (int u = 0; u < 8; ++u) {
                long long sv = __builtin_nontemporal_load((const long long*)(sj + np + u));
                int sx = (int)sv, sy = (int)(sv >> 32);
                kvn[u] = *(const uint2*)(KVb + (size_t)sx * 128 + 2 * lane);
                avn[u] = __builtin_nontemporal_load(ea + (size_t)sy * 64 + lane);
            }
        }
        float pp[8];
#pragma unroll
        for (int u = 0; u < 8; ++u) {
            float k0 = __uint_as_float(kv[u].x << 16);
            float k1 = __uint_as_float(kv[u].x & 0xffff0000u);
            pp[u] = q0 * k0 + q1 * k1 + wq * av[u];
        }
#pragma unroll
        for (int o = 32; o > 0; o >>= 1) {
#pragma unroll
            for (int u = 0; u < 8; ++u) pp[u] += __shfl_xor(pp[u], o);
        }
#pragma unroll
        for (int u = 0; u < 8; ++u) {
            float ex = __expf(pp[u] * ASCALE);
            accd += ex;
            t0 += ex * __uint_as_float(kv[u].y << 16);
            t1 += ex * __uint_as_float(kv[u].y & 0xffff0000u);
            sA += ex * av[u];
        }
        if (b + 1 < nb) {
#pragma unroll
            for (int u = 0; u < 8; ++u) { kv[u] = kvn[u]; av[u] = avn[u]; }
        }
        p = np;
    }
    for (; p + 4 <= end; p += 4) {
        float pp[4], aa[4], v0[4], v1[4];
#pragma unroll
        for (int u = 0; u < 4; ++u) {
            long long sv = __builtin_nontemporal_load((const long long*)(sj + p + u));
            int sx = (int)sv, sy = (int)(sv >> 32);
            uint2 kv2 = *(const uint2*)(KVb + (size_t)sx * 128 + 2 * lane);
            float a = __builtin_nontemporal_load(ea + (size_t)sy * 64 + lane);
            float k0 = __uint_as_float(kv2.x << 16);
            float k1 = __uint_as_float(kv2.x & 0xffff0000u);
            v0[u] = __uint_as_float(kv2.y << 16);
            v1[u] = __uint_as_float(kv2.y & 0xffff0000u);
            aa[u] = a;
            pp[u] = q0 * k0 + q1 * k1 + wq * a;
        }
#pragma unroll
        for (int o = 32; o > 0; o >>= 1) {
#pragma unroll
            for (int u = 0; u < 4; ++u) pp[u] += __shfl_xor(pp[u], o);
        }
#pragma unroll
        for (int u = 0; u < 4; ++u) {
            float ex = __expf(pp[u] * ASCALE);
            accd += ex;
            t0 += ex * v0[u];
            t1 += ex * v1[u];
            sA += ex * aa[u];
        }
    }
    for (; p < end; ++p) {
        long long sv = __builtin_nontemporal_load((const long long*)(sj + p));
        int sx = (int)sv, sy = (int)(sv >> 32);
        uint2 kv2 = *(const uint2*)(KVb + (size_t)sx * 128 + 2 * lane);
        float a = __builtin_nontemporal_load(ea + (size_t)sy * 64 + lane);
        float k0 = __uint_as_float(kv2.x << 16);
        float k1 = __uint_as_float(kv2.x & 0xffff0000u);
        float vv0 = __uint_as_float(kv2.y << 16);
        float vv1 = __uint_as_float(kv2.y & 0xffff0000u);
        float part = q0 * k0 + q1 * k1 + wq * a;
#pragma unroll
        for (int o = 32; o > 0; o >>= 1) part += __shfl_xor(part, o);
        float ex = __expf(part * ASCALE);
        accd += ex;
        t0 += ex * vv0;
        t1 += ex * vv1;
        sA += ex * a;
    }

    // accd is already lane-uniform (ex came from all-reduced alpha).

    // stage S (bf16) for MFMA
    Sb_l[wave * 64 + lane] = f2bf(sA);
    __syncthreads();   // orders Sb writes (all 4 waves) before MFMA reads

    // S@We: each wave computes 2 col-tiles of 16 for all 4 nodes.
    // B-fragments come straight from global (18KB table, L2/L1-hot).
    {
        int quad = lane >> 4, l16 = lane & 15;
        int arow = l16 & 3;     // A rows 4-15 duplicate rows 0-3; D rows 4-15 unused
        bf16x8 a0 = *(const bf16x8*)&Sb_l[arow * 64 + quad * 8];
        bf16x8 a1 = *(const bf16x8*)&Sb_l[arow * 64 + 32 + quad * 8];
#pragma unroll
        for (int c2 = 0; c2 < 2; ++c2) {
            int cn = wave * 2 + c2;
            int r = cn * 16 + l16;
            bf16x8 b0 = *(const bf16x8*)(WeTb + r * 72 + quad * 8);
            bf16x8 b1 = *(const bf16x8*)(WeTb + r * 72 + 32 + quad * 8);
            f32x4 acc = {};
            acc = __builtin_amdgcn_mfma_f32_16x16x32_bf16(a0, b0, acc, 0, 0, 0);
            acc = __builtin_amdgcn_mfma_f32_16x16x32_bf16(a1, b1, acc, 0, 0, 0);
            if (quad == 0) {
#pragma unroll
                for (int i = 0; i < 4; ++i)
                    att_l[i * 128 + cn * 16 + l16] = acc[i];
            }
        }
    }
    __syncthreads();

    float rcp = accd > 0.f ? 1.f / accd : 0.f;
    float a0f = (t0 + att_l[wave * 128 + lane]) * rcp + bfu(Erow[lane]);
    float a1f = (t1 + att_l[wave * 128 + 64 + lane]) * rcp + bfu(Erow[64 + lane]);

    float s = a0f + a1f;
#pragma unroll
    for (int o = 32; o > 0; o >>= 1) s += __shfl_xor(s, o);
    float mean = s * (1.f / 128.f);
    float d0 = a0f - mean, d1 = a1f - mean;
    float vs = d0 * d0 + d1 * d1;
#pragma unroll
    for (int o = 32; o > 0; o >>= 1) vs += __shfl_xor(vs, o);
    float inv = rsqrtf(vs * (1.f / 128.f) + 1e-5f);
    float n0 = d0 * inv * ln_g[lane] + ln_b[lane];
    float n1 = d1 * inv * ln_g[64 + lane] + ln_b[64 + lane];
    n0 = fmaxf(n0, 0.f);
    n1 = fmaxf(n1, 0.f);

    float g = bfu(Erow[320]);
    float r0 = bfu(Erow[128 + lane]);
    float r1 = bfu(Erow[192 + lane]);
    out[(size_t)node * 128 + lane] = g * n0 + (1.f - g) * r0;
    out[(size_t)node * 128 + 64 + lane] = g * n1 + (1.f - g) * r1;
}

// ---------------------------------------------------------------------------
extern "C" void kernel_launch(void* const* d_in, const int* in_sizes, int n_in,
                              void* d_out, int out_size, void* d_ws, size_t ws_size,
                              hipStream_t stream)
{
    const float* x     = (const float*)d_in[0];
    const int*   ei    = (const int*)d_in[1];
    const float* ea    = (const float*)d_in[2];
    const float* Wq    = (const float*)d_in[3];
    const float* bq    = (const float*)d_in[4];
    const float* Wk    = (const float*)d_in[5];
    const float* bk    = (const float*)d_in[6];
    const float* Wv    = (const float*)d_in[7];
    const float* bv    = (const float*)d_in[8];
    const float* We    = (const float*)d_in[9];
    const float* Wskip = (const float*)d_in[10];
    const float* bskip = (const float*)d_in[11];
    const float* ln_g  = (const float*)d_in[12];
    const float* ln_b  = (const float*)d_in[13];
    const float* Wres  = (const float*)d_in[14];
    const float* bres  = (const float*)d_in[15];
    const float* Wgate = (const float*)d_in[16];
    const float* bgate = (const float*)d_in[17];
    float* out = (float*)d_out;

    float* W = (float*)d_ws;
    size_t o = 0;
    auto falloc = [&](size_t e) { size_t r = o; o += e; return r; };
    size_t oPQ   = falloc((size_t)NN * 128);      // fp32 Q
    size_t oWQE  = falloc(8192);
    size_t oBQE  = falloc(64);
    size_t oBIAS = falloc(PC);
    size_t oKVB  = falloc((size_t)NN * 128);      // uint-sized (bf16 KV pairs)

    short* SB = (short*)(W + o);
    size_t oXB  = 0;                               // [NPAD*128] bf16
    size_t oWT  = oXB + (size_t)NPAD * 128;        // [768*128]  bf16
    size_t oWET = oWT + (size_t)PC * 128;          // [128*72]   bf16
    size_t oPE  = oWET + 128 * 72;                 // [NN*384]   bf16 epilogue panel
    size_t sh_total = oPE + (size_t)NN * 384;

    int* IB = (int*)(SB + ((sh_total + 1) & ~(size_t)1));
    size_t io = 0;
    auto ialloc = [&](size_t e) { size_t r = io; io += e; return r; };
    size_t oSJ   = ialloc((size_t)2 * EE);         // int2, 8B-aligned at IB+0
    size_t oDEG  = ialloc(NN);
    size_t oRS   = ialloc(NN + 1);
    size_t oCUR  = ialloc(NN);
    size_t oCS   = ialloc(64);

    hipMemsetAsync(IB + oDEG, 0, NN * sizeof(int), stream);

    k_wprep<<<33, 256, 0, stream>>>(Wq, bq, We, W + oWQE, W + oBQE);
    k_packx<<<(NPAD * 128 / 4 + 255) / 256, 256, 0, stream>>>(x, SB + oXB);
    k_packw<<<(PC * 128 + PC + 128 * 72 + 255) / 256, 256, 0, stream>>>(
        Wq, bq, Wk, bk, Wv, bv, Wskip, bskip, Wres, bres, Wgate, bgate,
        W + oWQE, W + oBQE, We, SB + oWT, W + oBIAS,
        (unsigned short*)(SB + oWET));

    dim3 ggrid(PC / 64, NPAD / 128);   // bn fastest -> A-tile L2 reuse
    k_gemm<<<ggrid, 256, 0, stream>>>(SB + oXB, SB + oWT, W + oBIAS, W + oPQ,
                                      (unsigned short*)(SB + oPE),
                                      (unsigned short*)(W + oKVB));

    k_hist<<<(EE + 255) / 256, 256, 0, stream>>>(ei, IB + oDEG, EE);
    k_scan1<<<49, 256, 0, stream>>>(IB + oDEG, IB + oRS, IB + oCS, NN);
    k_scan2<<<1, 64, 0, stream>>>(IB + oCS, 49);
    k_scan3<<<(NN + 256) / 256, 256, 0, stream>>>(IB + oRS, IB + oCS, IB + oCUR, NN, EE);
    k_scatter<<<(EE + 255) / 256, 256, 0, stream>>>(ei, IB + oCUR, (int2*)(IB + oSJ), EE);

    k_attn_fused<<<NN / 4, 256, 0, stream>>>(
        W + oPQ, (const unsigned short*)(SB + oPE),
        (const unsigned int*)(W + oKVB), ea,
        (const unsigned short*)(SB + oWET),
        IB + oRS, (const int2*)(IB + oSJ), ln_g, ln_b, out);
}

// Round 7
// 578.192 us; speedup vs baseline: 1.0716x; 1.0716x over previous
//
#include <hip/hip_runtime.h>
#include <math.h>

#define NN 50000
#define EE 800000
#define NPAD 50048           // 391 * 128
#define PC 768               // packed GEMM column count
// GEMM col map: [0,128) Q -> Pq fp32 | [128,384) K/V -> KVb bf16 |
//               [384,512) SKIP, [512,640) RES, [640,704) WEQ, 704 GATE -> Pe bf16
// Pe row (384 ushorts): [0,128) skip | [128,256) res | [256,320) weq | 320 gate
// KVb[node] = 128 dwords, INTERLEAVED: dword 2c   = (bf16 K[c] lo, bf16 K[c+64] hi)
//                                      dword 2c+1 = (bf16 V[c] lo, bf16 V[c+64] hi)
// attn lane reads uint2 at dword 2*lane -> (K pair, V pair).

typedef short bf16x8 __attribute__((ext_vector_type(8)));
typedef float f32x4 __attribute__((ext_vector_type(4)));

#define ASCALE 0.08838834764831845f   // 1/sqrt(128)

__device__ inline unsigned short f2bf(float f)
{
    unsigned u = __float_as_uint(f);
    u = u + 0x7fff + ((u >> 16) & 1);   // RNE
    return (unsigned short)(u >> 16);
}

__device__ inline float bfu(unsigned short us)
{
    return __uint_as_float((unsigned)us << 16);
}

// ---------------------------------------------------------------------------
// K0: weight prep  wqe[r][m] = sum_c Wq[r][c] * We[m][c]   ([128,64])
// ---------------------------------------------------------------------------
__global__ __launch_bounds__(256) void k_wprep(const float* __restrict__ Wq,
                                               const float* __restrict__ bq,
                                               const float* __restrict__ We,
                                               float* __restrict__ wqe,
                                               float* __restrict__ bqe)
{
    int idx = blockIdx.x * 256 + threadIdx.x;
    if (idx < 8192) {
        int r = idx >> 6, m = idx & 63;
        float acc = 0.f;
        for (int c = 0; c < 128; ++c) acc += Wq[r * 128 + c] * We[m * 128 + c];
        wqe[r * 64 + m] = acc;
    } else if (idx < 8256) {
        int m = idx - 8192;
        float acc = 0.f;
        for (int c = 0; c < 128; ++c) acc += bq[c] * We[m * 128 + c];
        bqe[m] = acc;
    }
}

// ---------------------------------------------------------------------------
// K1a: pack x -> bf16 [NPAD][128], zero pad rows
// ---------------------------------------------------------------------------
__global__ __launch_bounds__(256) void k_packx(const float* __restrict__ x,
                                               short* __restrict__ Xb)
{
    int t = blockIdx.x * 256 + threadIdx.x;
    int base = t * 4;
    if (base >= NPAD * 128) return;
    short s0 = 0, s1 = 0, s2 = 0, s3 = 0;
    if (base < NN * 128) {
        const float4 v = *(const float4*)(x + base);
        s0 = f2bf(v.x); s1 = f2bf(v.y); s2 = f2bf(v.z); s3 = f2bf(v.w);
    }
    short4 o; o.x = s0; o.y = s1; o.z = s2; o.w = s3;
    *(short4*)(Xb + base) = o;
}

// ---------------------------------------------------------------------------
// K1b: pack transposed weight WT[col][k] (bf16 [768][128]) + bias[768]
//      + WeTb[c][kk] (bf16 [128][72], row-padded, zeros in pad)
// ---------------------------------------------------------------------------
__global__ __launch_bounds__(256) void k_packw(
    const float* __restrict__ Wq, const float* __restrict__ bq,
    const float* __restrict__ Wk, const float* __restrict__ bk,
    const float* __restrict__ Wv, const float* __restrict__ bv,
    const float* __restrict__ Wskip, const float* __restrict__ bskip,
    const float* __restrict__ Wres, const float* __restrict__ bres,
    const float* __restrict__ Wgate, const float* __restrict__ bgate,
    const float* __restrict__ wqe, const float* __restrict__ bqe,
    const float* __restrict__ We,
    short* __restrict__ WT, float* __restrict__ bias,
    unsigned short* __restrict__ WeTb)
{
    int idx = blockIdx.x * 256 + threadIdx.x;
    if (idx < PC * 128) {
        int col = idx >> 7, k = idx & 127;
        float v;
        if (col < 128)      v = Wq[k * 128 + col];
        else if (col < 256) v = Wk[k * 128 + (col - 128)];
        else if (col < 384) v = Wv[k * 128 + (col - 256)];
        else if (col < 512) v = Wskip[k * 128 + (col - 384)];
        else if (col < 640) v = Wres[k * 128 + (col - 512)];
        else if (col < 704) v = wqe[k * 64 + (col - 640)];
        else if (col == 704) v = Wgate[k];
        else                v = 0.f;
        WT[col * 128 + k] = (short)f2bf(v);
    } else if (idx < PC * 128 + PC) {
        int col = idx - PC * 128;
        float b;
        if (col < 128)      b = bq[col];
        else if (col < 256) b = bk[col - 128];
        else if (col < 384) b = bv[col - 256];
        else if (col < 512) b = bskip[col - 384];
        else if (col < 640) b = bres[col - 512];
        else if (col < 704) b = bqe[col - 640];
        else if (col == 704) b = bgate[0];
        else                b = 0.f;
        bias[col] = b;
    } else if (idx < PC * 128 + PC + 128 * 72) {
        int i2 = idx - (PC * 128 + PC);
        int c = i2 / 72, kk = i2 % 72;
        WeTb[i2] = (kk < 64) ? f2bf(We[kk * 128 + c]) : (unsigned short)0;
    }
}

// ---------------------------------------------------------------------------
// K2: MFMA GEMM. Block tile 128x64, grid (bn fastest) for A-tile L2 reuse.
// bn 0-1 -> Pq fp32; bn 2-5 -> KVb bf16 (interleaved); bn 6-11 -> Pe bf16.
// ---------------------------------------------------------------------------
#define LROW 136
__global__ __launch_bounds__(256) void k_gemm(const short* __restrict__ Xb,
                                              const short* __restrict__ WT,
                                              const float* __restrict__ bias,
                                              float* __restrict__ Pq,
                                              unsigned short* __restrict__ Pe,
                                              unsigned short* __restrict__ KVb16)
{
    __shared__ short Al[128 * LROW];
    __shared__ short Bl[64 * LROW];

    int bn = blockIdx.x;          // 12 col tiles (fastest -> A reuse in L2)
    int bm = blockIdx.y;          // 391 row tiles
    int tid = threadIdx.x;

    const short* gA = Xb + (size_t)bm * 128 * 128;
    const short* gB = WT + (size_t)bn * 64 * 128;

#pragma unroll
    for (int it = 0; it < 8; ++it) {
        int g = it * 256 + tid;           // unit = 8 shorts (16 B)
        int row = g >> 4, c8 = g & 15;
        *(bf16x8*)&Al[row * LROW + c8 * 8] = *(const bf16x8*)(gA + g * 8);
    }
#pragma unroll
    for (int it = 0; it < 4; ++it) {
        int g = it * 256 + tid;
        int row = g >> 4, c8 = g & 15;
        *(bf16x8*)&Bl[row * LROW + c8 * 8] = *(const bf16x8*)(gB + g * 8);
    }
    __syncthreads();

    int wave = tid >> 6, lane = tid & 63;
    int quad = lane >> 4, l16 = lane & 15;
    int r0 = wave * 32;

    f32x4 acc[2][4] = {};
#pragma unroll
    for (int ks = 0; ks < 4; ++ks) {
        int k0 = ks * 32 + quad * 8;
        bf16x8 af0 = *(const bf16x8*)&Al[(r0 + l16) * LROW + k0];
        bf16x8 af1 = *(const bf16x8*)&Al[(r0 + 16 + l16) * LROW + k0];
#pragma unroll
        for (int cn = 0; cn < 4; ++cn) {
            bf16x8 bfr = *(const bf16x8*)&Bl[(cn * 16 + l16) * LROW + k0];
            acc[0][cn] = __builtin_amdgcn_mfma_f32_16x16x32_bf16(af0, bfr, acc[0][cn], 0, 0, 0);
            acc[1][cn] = __builtin_amdgcn_mfma_f32_16x16x32_bf16(af1, bfr, acc[1][cn], 0, 0, 0);
        }
    }

    bool isKV = (bn >= 2 && bn <= 5);
#pragma unroll
    for (int half = 0; half < 2; ++half) {
        int growb = bm * 128 + r0 + half * 16 + quad * 4;
#pragma unroll
        for (int cn = 0; cn < 4; ++cn) {
            int gcol = bn * 64 + cn * 16 + l16;
            float b = bias[gcol];
#pragma unroll
            for (int i = 0; i < 4; ++i) {
                int grow = growb + i;
                if (grow < NN) {
                    float v = acc[half][cn][i] + b;
                    if (bn < 2) {
                        Pq[(size_t)grow * 128 + gcol] = v;
                    } else if (isKV) {
                        // interleaved: K col c -> ushort 4c/4c+1, V col c -> 4c+2/4c+3
                        int c, sub;
                        if (gcol < 192)      { c = gcol - 128; sub = 0; }
                        else if (gcol < 256) { c = gcol - 192; sub = 1; }
                        else if (gcol < 320) { c = gcol - 256; sub = 2; }
                        else                 { c = gcol - 320; sub = 3; }
                        KVb16[(size_t)grow * 256 + c * 4 + sub] = f2bf(v);
                    } else if (gcol <= 704) {
                        if (gcol == 704) v = 1.f / (1.f + __expf(-v));
                        Pe[(size_t)grow * 384 + (gcol - 384)] = f2bf(v);
                    }
                }
            }
        }
    }
}

// ---------------------------------------------------------------------------
// CSR build
// ---------------------------------------------------------------------------
__global__ __launch_bounds__(256) void k_hist(const int* __restrict__ ei,
                                              int* __restrict__ deg, int E)
{
    int e = blockIdx.x * 256 + threadIdx.x;
    if (e < E) atomicAdd(&deg[ei[E + e]], 1);
}

__global__ __launch_bounds__(256) void k_scan1(const int* __restrict__ deg,
                                               int* __restrict__ rs,
                                               int* __restrict__ cs, int n)
{
    __shared__ int sh[256];
    int base = blockIdx.x * 1024;
    int t = threadIdx.x;
    int idx = base + t * 4;
    int v[4];
#pragma unroll
    for (int k = 0; k < 4; ++k) v[k] = (idx + k < n) ? deg[idx + k] : 0;
    int sum = v[0] + v[1] + v[2] + v[3];
    sh[t] = sum;
    __syncthreads();
    for (int off = 1; off < 256; off <<= 1) {
        int add = (t >= off) ? sh[t - off] : 0;
        __syncthreads();
        sh[t] += add;
        __syncthreads();
    }
    int run = sh[t] - sum;
    if (t == 255) cs[blockIdx.x] = sh[255];
#pragma unroll
    for (int k = 0; k < 4; ++k) {
        if (idx + k < n) rs[idx + k] = run;
        run += v[k];
    }
}

__global__ void k_scan2(int* __restrict__ cs, int nc)
{
    __shared__ int sh[64];
    int t = threadIdx.x;
    sh[t] = (t < nc) ? cs[t] : 0;
    __syncthreads();
    if (t == 0) {
        int acc = 0;
        for (int i = 0; i < nc; ++i) { int v = sh[i]; sh[i] = acc; acc += v; }
    }
    __syncthreads();
    if (t < nc) cs[t] = sh[t];
}

__global__ __launch_bounds__(256) void k_scan3(int* __restrict__ rs,
                                               const int* __restrict__ cs,
                                               int* __restrict__ cur, int n, int E)
{
    int i = blockIdx.x * 256 + threadIdx.x;
    if (i < n) {
        int v = rs[i] + cs[i >> 10];
        rs[i] = v;
        cur[i] = v;
    } else if (i == n) {
        rs[n] = E;
    }
}

__global__ __launch_bounds__(256) void k_scatter(const int* __restrict__ ei,
                                                 int* __restrict__ cur,
                                                 int2* __restrict__ sj, int E)
{
    int e = blockIdx.x * 256 + threadIdx.x;
    if (e < E) {
        int d = ei[E + e];
        int pos = atomicAdd(&cur[d], 1);
        int2 v; v.x = ei[e]; v.y = e;
        sj[pos] = v;
    }
}

// ---------------------------------------------------------------------------
// K3: fused attention + epilogue. One wave per node, 4 nodes/block.
// R2-verified structure (best measured: 126.8us): 8x/4x/1x unrolled gather,
// interleaved bf16 KV (1 dwordx2/edge) + fp32 ea (nontemporal), Pe bf16
// epilogue panel, cooperative S@We MFMA epilogue.
// Failed experiments (do not retry without new evidence):
//  - degree-sorted perm (R3): 64-bin atomics cost +225us; zero gather gain
//  - per-wave MFMA epilogue (R4): +33us, serial vmcnt on B-frags
//  - register SW-pipeline (R5): +55us, VGPR 68 -> occupancy 32%
//  - two-edges-per-wave (R6): absmax 0.0625 > 0.0534 (FP reorder)
// ---------------------------------------------------------------------------
__global__ __launch_bounds__(256) void k_attn_fused(
    const float* __restrict__ Pq, const unsigned short* __restrict__ Pe,
    const unsigned int* __restrict__ KVb,
    const float* __restrict__ ea, const unsigned short* __restrict__ WeTb,
    const int* __restrict__ rs, const int2* __restrict__ sj,
    const float* __restrict__ ln_g, const float* __restrict__ ln_b,
    float* __restrict__ out)
{
    __shared__ unsigned short Sb_l[4 * 64];      // [node][k] bf16
    __shared__ float att_l[4 * 128];             // S@We result

    int tid = threadIdx.x;
    int wave = tid >> 6, lane = tid & 63;
    int node = blockIdx.x * 4 + wave;            // grid is exactly NN/4

    const float* Qrow = Pq + (size_t)node * 128;
    const unsigned short* Erow = Pe + (size_t)node * 384;
    float q0 = Qrow[lane];
    float q1 = Qrow[64 + lane];
    float wq = bfu(Erow[256 + lane]);

    float accd = 0.f, t0 = 0.f, t1 = 0.f, sA = 0.f;
    int beg = rs[node], end = rs[node + 1];

    int p = beg;
    for (; p + 8 <= end; p += 8) {
        float pp[8], aa[8], v0[8], v1[8];
#pragma unroll
        for (int u = 0; u < 8; ++u) {
            long long sv = __builtin_nontemporal_load((const long long*)(sj + p + u));
            int sx = (int)sv, sy = (int)(sv >> 32);
            uint2 kv2 = *(const uint2*)(KVb + (size_t)sx * 128 + 2 * lane);
            float a = __builtin_nontemporal_load(ea + (size_t)sy * 64 + lane);
            float k0 = __uint_as_float(kv2.x << 16);
            float k1 = __uint_as_float(kv2.x & 0xffff0000u);
            v0[u] = __uint_as_float(kv2.y << 16);
            v1[u] = __uint_as_float(kv2.y & 0xffff0000u);
            aa[u] = a;
            pp[u] = q0 * k0 + q1 * k1 + wq * a;
        }
#pragma unroll
        for (int o = 32; o > 0; o >>= 1) {
#pragma unroll
            for (int u = 0; u < 8; ++u) pp[u] += __shfl_xor(pp[u], o);
        }
#pragma unroll
        for (int u = 0; u < 8; ++u) {
            float ex = __expf(pp[u] * ASCALE);
            accd += ex;
            t0 += ex * v0[u];
            t1 += ex * v1[u];
            sA += ex * aa[u];
        }
    }
    for (; p + 4 <= end; p += 4) {
        float pp[4], aa[4], v0[4], v1[4];
#pragma unroll
        for (int u = 0; u < 4; ++u) {
            long long sv = __builtin_nontemporal_load((const long long*)(sj + p + u));
            int sx = (int)sv, sy = (int)(sv >> 32);
            uint2 kv2 = *(const uint2*)(KVb + (size_t)sx * 128 + 2 * lane);
            float a = __builtin_nontemporal_load(ea + (size_t)sy * 64 + lane);
            float k0 = __uint_as_float(kv2.x << 16);
            float k1 = __uint_as_float(kv2.x & 0xffff0000u);
            v0[u] = __uint_as_float(kv2.y << 16);
            v1[u] = __uint_as_float(kv2.y & 0xffff0000u);
            aa[u] = a;
            pp[u] = q0 * k0 + q1 * k1 + wq * a;
        }
#pragma unroll
        for (int o = 32; o > 0; o >>= 1) {
#pragma unroll
            for (int u = 0; u < 4; ++u) pp[u] += __shfl_xor(pp[u], o);
        }
#pragma unroll
        for (int u = 0; u < 4; ++u) {
            float ex = __expf(pp[u] * ASCALE);
            accd += ex;
            t0 += ex * v0[u];
            t1 += ex * v1[u];
            sA += ex * aa[u];
        }
    }
    for (; p < end; ++p) {
        long long sv = __builtin_nontemporal_load((const long long*)(sj + p));
        int sx = (int)sv, sy = (int)(sv >> 32);
        uint2 kv2 = *(const uint2*)(KVb + (size_t)sx * 128 + 2 * lane);
        float a = __builtin_nontemporal_load(ea + (size_t)sy * 64 + lane);
        float k0 = __uint_as_float(kv2.x << 16);
        float k1 = __uint_as_float(kv2.x & 0xffff0000u);
        float vv0 = __uint_as_float(kv2.y << 16);
        float vv1 = __uint_as_float(kv2.y & 0xffff0000u);
        float part = q0 * k0 + q1 * k1 + wq * a;
#pragma unroll
        for (int o = 32; o > 0; o >>= 1) part += __shfl_xor(part, o);
        float ex = __expf(part * ASCALE);
        accd += ex;
        t0 += ex * vv0;
        t1 += ex * vv1;
        sA += ex * a;
    }

    // accd is already lane-uniform (ex came from all-reduced alpha).

    // stage S (bf16) for MFMA
    Sb_l[wave * 64 + lane] = f2bf(sA);
    __syncthreads();   // orders Sb writes (all 4 waves) before MFMA reads

    // S@We: each wave computes 2 col-tiles of 16 for all 4 nodes.
    // B-fragments come straight from global (18KB table, L2/L1-hot).
    {
        int quad = lane >> 4, l16 = lane & 15;
        int arow = l16 & 3;     // A rows 4-15 duplicate rows 0-3; D rows 4-15 unused
        bf16x8 a0 = *(const bf16x8*)&Sb_l[arow * 64 + quad * 8];
        bf16x8 a1 = *(const bf16x8*)&Sb_l[arow * 64 + 32 + quad * 8];
#pragma unroll
        for (int c2 = 0; c2 < 2; ++c2) {
            int cn = wave * 2 + c2;
            int r = cn * 16 + l16;
            bf16x8 b0 = *(const bf16x8*)(WeTb + r * 72 + quad * 8);
            bf16x8 b1 = *(const bf16x8*)(WeTb + r * 72 + 32 + quad * 8);
            f32x4 acc = {};
            acc = __builtin_amdgcn_mfma_f32_16x16x32_bf16(a0, b0, acc, 0, 0, 0);
            acc = __builtin_amdgcn_mfma_f32_16x16x32_bf16(a1, b1, acc, 0, 0, 0);
            if (quad == 0) {
#pragma unroll
                for (int i = 0; i < 4; ++i)
                    att_l[i * 128 + cn * 16 + l16] = acc[i];
            }
        }
    }
    __syncthreads();

    float rcp = accd > 0.f ? 1.f / accd : 0.f;
    float a0f = (t0 + att_l[wave * 128 + lane]) * rcp + bfu(Erow[lane]);
    float a1f = (t1 + att_l[wave * 128 + 64 + lane]) * rcp + bfu(Erow[64 + lane]);

    float s = a0f + a1f;
#pragma unroll
    for (int o = 32; o > 0; o >>= 1) s += __shfl_xor(s, o);
    float mean = s * (1.f / 128.f);
    float d0 = a0f - mean, d1 = a1f - mean;
    float vs = d0 * d0 + d1 * d1;
#pragma unroll
    for (int o = 32; o > 0; o >>= 1) vs += __shfl_xor(vs, o);
    float inv = rsqrtf(vs * (1.f / 128.f) + 1e-5f);
    float n0 = d0 * inv * ln_g[lane] + ln_b[lane];
    float n1 = d1 * inv * ln_g[64 + lane] + ln_b[64 + lane];
    n0 = fmaxf(n0, 0.f);
    n1 = fmaxf(n1, 0.f);

    float g = bfu(Erow[320]);
    float r0 = bfu(Erow[128 + lane]);
    float r1 = bfu(Erow[192 + lane]);
    out[(size_t)node * 128 + lane] = g * n0 + (1.f - g) * r0;
    out[(size_t)node * 128 + 64 + lane] = g * n1 + (1.f - g) * r1;
}

// ---------------------------------------------------------------------------
extern "C" void kernel_launch(void* const* d_in, const int* in_sizes, int n_in,
                              void* d_out, int out_size, void* d_ws, size_t ws_size,
                              hipStream_t stream)
{
    const float* x     = (const float*)d_in[0];
    const int*   ei    = (const int*)d_in[1];
    const float* ea    = (const float*)d_in[2];
    const float* Wq    = (const float*)d_in[3];
    const float* bq    = (const float*)d_in[4];
    const float* Wk    = (const float*)d_in[5];
    const float* bk    = (const float*)d_in[6];
    const float* Wv    = (const float*)d_in[7];
    const float* bv    = (const float*)d_in[8];
    const float* We    = (const float*)d_in[9];
    const float* Wskip = (const float*)d_in[10];
    const float* bskip = (const float*)d_in[11];
    const float* ln_g  = (const float*)d_in[12];
    const float* ln_b  = (const float*)d_in[13];
    const float* Wres  = (const float*)d_in[14];
    const float* bres  = (const float*)d_in[15];
    const float* Wgate = (const float*)d_in[16];
    const float* bgate = (const float*)d_in[17];
    float* out = (float*)d_out;

    float* W = (float*)d_ws;
    size_t o = 0;
    auto falloc = [&](size_t e) { size_t r = o; o += e; return r; };
    size_t oPQ   = falloc((size_t)NN * 128);      // fp32 Q
    size_t oWQE  = falloc(8192);
    size_t oBQE  = falloc(64);
    size_t oBIAS = falloc(PC);
    size_t oKVB  = falloc((size_t)NN * 128);      // uint-sized (bf16 KV pairs)

    short* SB = (short*)(W + o);
    size_t oXB  = 0;                               // [NPAD*128] bf16
    size_t oWT  = oXB + (size_t)NPAD * 128;        // [768*128]  bf16
    size_t oWET = oWT + (size_t)PC * 128;          // [128*72]   bf16
    size_t oPE  = oWET + 128 * 72;                 // [NN*384]   bf16 epilogue panel
    size_t sh_total = oPE + (size_t)NN * 384;

    int* IB = (int*)(SB + ((sh_total + 1) & ~(size_t)1));
    size_t io = 0;
    auto ialloc = [&](size_t e) { size_t r = io; io += e; return r; };
    size_t oSJ   = ialloc((size_t)2 * EE);         // int2, 8B-aligned at IB+0
    size_t oDEG  = ialloc(NN);
    size_t oRS   = ialloc(NN + 1);
    size_t oCUR  = ialloc(NN);
    size_t oCS   = ialloc(64);

    hipMemsetAsync(IB + oDEG, 0, NN * sizeof(int), stream);

    k_wprep<<<33, 256, 0, stream>>>(Wq, bq, We, W + oWQE, W + oBQE);
    k_packx<<<(NPAD * 128 / 4 + 255) / 256, 256, 0, stream>>>(x, SB + oXB);
    k_packw<<<(PC * 128 + PC + 128 * 72 + 255) / 256, 256, 0, stream>>>(
        Wq, bq, Wk, bk, Wv, bv, Wskip, bskip, Wres, bres, Wgate, bgate,
        W + oWQE, W + oBQE, We, SB + oWT, W + oBIAS,
        (unsigned short*)(SB + oWET));

    dim3 ggrid(PC / 64, NPAD / 128);   // bn fastest -> A-tile L2 reuse
    k_gemm<<<ggrid, 256, 0, stream>>>(SB + oXB, SB + oWT, W + oBIAS, W + oPQ,
                                      (unsigned short*)(SB + oPE),
                                      (unsigned short*)(W + oKVB));

    k_hist<<<(EE + 255) / 256, 256, 0, stream>>>(ei, IB + oDEG, EE);
    k_scan1<<<49, 256, 0, stream>>>(IB + oDEG, IB + oRS, IB + oCS, NN);
    k_scan2<<<1, 64, 0, stream>>>(IB + oCS, 49);
    k_scan3<<<(NN + 256) / 256, 256, 0, stream>>>(IB + oRS, IB + oCS, IB + oCUR, NN, EE);
    k_scatter<<<(EE + 255) / 256, 256, 0, stream>>>(ei, IB + oCUR, (int2*)(IB + oSJ), EE);

    k_attn_fused<<<NN / 4, 256, 0, stream>>>(
        W + oPQ, (const unsigned short*)(SB + oPE),
        (const unsigned int*)(W + oKVB), ea,
        (const unsigned short*)(SB + oWET),
        IB + oRS, (const int2*)(IB + oSJ), ln_g, ln_b, out);
}

// Round 8
// 547.683 us; speedup vs baseline: 1.1313x; 1.0557x over previous
//
#include <hip/hip_runtime.h>
#include <math.h>

#define NN 50000
#define EE 800000
#define NPAD 50048           // 391 * 128
#define PC 768               // packed GEMM column count
// GEMM col map: [0,128) Q -> Pq fp32
//   [128,384) KV pair-interleaved: col 128+4c+s, s=0:K[c] 1:K[c+64] 2:V[c] 3:V[c+64]
//             -> KVb ushort (col-128) directly (KVb dword 2c = K[c]|K[c+64],
//                dword 2c+1 = V[c]|V[c+64]; attn lane reads uint2 at dword 2*lane)
//   [384,512) SKIP, [512,640) RES, [640,704) WEQ, 704 GATE -> Pe bf16
// Pe row (384 ushorts): [0,128) skip | [128,256) res | [256,320) weq | 320 gate
// k_gemm uses OPERAND-SWAPPED MFMA (D = C^T): each thread holds 1 row x 4
// consecutive cols -> packed stores (float4 / uint2), 8 stores/thread vs 32.

typedef short bf16x8 __attribute__((ext_vector_type(8)));
typedef float f32x4 __attribute__((ext_vector_type(4)));

#define ASCALE 0.08838834764831845f   // 1/sqrt(128)

__device__ inline unsigned short f2bf(float f)
{
    unsigned u = __float_as_uint(f);
    u = u + 0x7fff + ((u >> 16) & 1);   // RNE
    return (unsigned short)(u >> 16);
}

__device__ inline float bfu(unsigned short us)
{
    return __uint_as_float((unsigned)us << 16);
}

// ---------------------------------------------------------------------------
// K0: fused prep. Blocks [0, NXB): pack x -> bf16 [NPAD][128] (zero pad).
// Blocks [NXB, NXB+33): wqe[r][m] = sum_c Wq[r][c]*We[m][c] + bqe.
// ---------------------------------------------------------------------------
#define NXB (NPAD * 128 / 4 / 256)    // 6256
__global__ __launch_bounds__(256) void k_prep(const float* __restrict__ x,
                                              short* __restrict__ Xb,
                                              const float* __restrict__ Wq,
                                              const float* __restrict__ bq,
                                              const float* __restrict__ We,
                                              float* __restrict__ wqe,
                                              float* __restrict__ bqe)
{
    if (blockIdx.x < NXB) {
        int t = blockIdx.x * 256 + threadIdx.x;
        int base = t * 4;
        short s0 = 0, s1 = 0, s2 = 0, s3 = 0;
        if (base < NN * 128) {
            const float4 v = *(const float4*)(x + base);
            s0 = f2bf(v.x); s1 = f2bf(v.y); s2 = f2bf(v.z); s3 = f2bf(v.w);
        }
        short4 o; o.x = s0; o.y = s1; o.z = s2; o.w = s3;
        *(short4*)(Xb + base) = o;
    } else {
        int idx = (blockIdx.x - NXB) * 256 + threadIdx.x;
        if (idx < 8192) {
            int r = idx >> 6, m = idx & 63;
            float acc = 0.f;
            for (int c = 0; c < 128; ++c) acc += Wq[r * 128 + c] * We[m * 128 + c];
            wqe[r * 64 + m] = acc;
        } else if (idx < 8256) {
            int m = idx - 8192;
            float acc = 0.f;
            for (int c = 0; c < 128; ++c) acc += bq[c] * We[m * 128 + c];
            bqe[m] = acc;
        }
    }
}

// ---------------------------------------------------------------------------
// K1b: pack transposed weight WT[col][k] (bf16 [768][128]) + bias[768]
//      + WeTb[c][kk] (bf16 [128][72], row-padded, zeros in pad)
// ---------------------------------------------------------------------------
__global__ __launch_bounds__(256) void k_packw(
    const float* __restrict__ Wq, const float* __restrict__ bq,
    const float* __restrict__ Wk, const float* __restrict__ bk,
    const float* __restrict__ Wv, const float* __restrict__ bv,
    const float* __restrict__ Wskip, const float* __restrict__ bskip,
    const float* __restrict__ Wres, const float* __restrict__ bres,
    const float* __restrict__ Wgate, const float* __restrict__ bgate,
    const float* __restrict__ wqe, const float* __restrict__ bqe,
    const float* __restrict__ We,
    short* __restrict__ WT, float* __restrict__ bias,
    unsigned short* __restrict__ WeTb)
{
    int idx = blockIdx.x * 256 + threadIdx.x;
    if (idx < PC * 128) {
        int col = idx >> 7, k = idx & 127;
        float v;
        if (col < 128)      v = Wq[k * 128 + col];
        else if (col < 384) {
            int t = col - 128, c = t >> 2, s = t & 3;
            v = (s == 0) ? Wk[k * 128 + c] : (s == 1) ? Wk[k * 128 + c + 64]
              : (s == 2) ? Wv[k * 128 + c] : Wv[k * 128 + c + 64];
        }
        else if (col < 512) v = Wskip[k * 128 + (col - 384)];
        else if (col < 640) v = Wres[k * 128 + (col - 512)];
        else if (col < 704) v = wqe[k * 64 + (col - 640)];
        else if (col == 704) v = Wgate[k];
        else                v = 0.f;
        WT[col * 128 + k] = (short)f2bf(v);
    } else if (idx < PC * 128 + PC) {
        int col = idx - PC * 128;
        float b;
        if (col < 128)      b = bq[col];
        else if (col < 384) {
            int t = col - 128, c = t >> 2, s = t & 3;
            b = (s == 0) ? bk[c] : (s == 1) ? bk[c + 64]
              : (s == 2) ? bv[c] : bv[c + 64];
        }
        else if (col < 512) b = bskip[col - 384];
        else if (col < 640) b = bres[col - 512];
        else if (col < 704) b = bqe[col - 640];
        else if (col == 704) b = bgate[0];
        else                b = 0.f;
        bias[col] = b;
    } else if (idx < PC * 128 + PC + 128 * 72) {
        int i2 = idx - (PC * 128 + PC);
        int c = i2 / 72, kk = i2 % 72;
        WeTb[i2] = (kk < 64) ? f2bf(We[kk * 128 + c]) : (unsigned short)0;
    }
}

// ---------------------------------------------------------------------------
// K2: MFMA GEMM, operand-swapped (D = C^T). Block tile 128x64, bn fastest.
// Thread (quad,l16) per (half,cn): row grow = bm*128+r0+half*16+l16,
// cols colbase..colbase+3 (colbase = bn*64+cn*16+quad*4) -> packed stores.
// bn 0-1 -> Pq fp32 (float4); bn 2-5 -> KVb bf16 (uint2); bn 6-11 -> Pe (uint2).
// ---------------------------------------------------------------------------
#define LROW 136
__global__ __launch_bounds__(256) void k_gemm(const short* __restrict__ Xb,
                                              const short* __restrict__ WT,
                                              const float* __restrict__ bias,
                                              float* __restrict__ Pq,
                                              unsigned short* __restrict__ Pe,
                                              unsigned short* __restrict__ KVb16)
{
    __shared__ short Al[128 * LROW];
    __shared__ short Bl[64 * LROW];

    int bn = blockIdx.x;          // 12 col tiles (fastest -> A reuse in L2)
    int bm = blockIdx.y;          // 391 row tiles
    int tid = threadIdx.x;

    const short* gA = Xb + (size_t)bm * 128 * 128;
    const short* gB = WT + (size_t)bn * 64 * 128;

#pragma unroll
    for (int it = 0; it < 8; ++it) {
        int g = it * 256 + tid;           // unit = 8 shorts (16 B)
        int row = g >> 4, c8 = g & 15;
        *(bf16x8*)&Al[row * LROW + c8 * 8] = *(const bf16x8*)(gA + g * 8);
    }
#pragma unroll
    for (int it = 0; it < 4; ++it) {
        int g = it * 256 + tid;
        int row = g >> 4, c8 = g & 15;
        *(bf16x8*)&Bl[row * LROW + c8 * 8] = *(const bf16x8*)(gB + g * 8);
    }
    __syncthreads();

    int wave = tid >> 6, lane = tid & 63;
    int quad = lane >> 4, l16 = lane & 15;
    int r0 = wave * 32;

    f32x4 acc[2][4] = {};
#pragma unroll
    for (int ks = 0; ks < 4; ++ks) {
        int k0 = ks * 32 + quad * 8;
        bf16x8 af0 = *(const bf16x8*)&Al[(r0 + l16) * LROW + k0];
        bf16x8 af1 = *(const bf16x8*)&Al[(r0 + 16 + l16) * LROW + k0];
#pragma unroll
        for (int cn = 0; cn < 4; ++cn) {
            bf16x8 bfr = *(const bf16x8*)&Bl[(cn * 16 + l16) * LROW + k0];
            // swapped operands: D = (A*B)^T -> lane l16 = X-row, reg = col
            acc[0][cn] = __builtin_amdgcn_mfma_f32_16x16x32_bf16(bfr, af0, acc[0][cn], 0, 0, 0);
            acc[1][cn] = __builtin_amdgcn_mfma_f32_16x16x32_bf16(bfr, af1, acc[1][cn], 0, 0, 0);
        }
    }

    bool isKV = (bn >= 2 && bn <= 5);
#pragma unroll
    for (int half = 0; half < 2; ++half) {
        int grow = bm * 128 + r0 + half * 16 + l16;
        if (grow < NN) {
#pragma unroll
            for (int cn = 0; cn < 4; ++cn) {
                int colbase = bn * 64 + cn * 16 + quad * 4;
                const float4 b4 = *(const float4*)(bias + colbase);
                float v0 = acc[half][cn][0] + b4.x;
                float v1 = acc[half][cn][1] + b4.y;
                float v2 = acc[half][cn][2] + b4.z;
                float v3 = acc[half][cn][3] + b4.w;
                if (bn < 2) {
                    float4 o; o.x = v0; o.y = v1; o.z = v2; o.w = v3;
                    *(float4*)(Pq + (size_t)grow * 128 + colbase) = o;
                } else if (isKV) {
                    uint2 o;
                    o.x = (unsigned)f2bf(v0) | ((unsigned)f2bf(v1) << 16);
                    o.y = (unsigned)f2bf(v2) | ((unsigned)f2bf(v3) << 16);
                    *(uint2*)(KVb16 + (size_t)grow * 256 + (colbase - 128)) = o;
                } else {
                    if (colbase == 704) v0 = 1.f / (1.f + __expf(-v0));
                    uint2 o;
                    o.x = (unsigned)f2bf(v0) | ((unsigned)f2bf(v1) << 16);
                    o.y = (unsigned)f2bf(v2) | ((unsigned)f2bf(v3) << 16);
                    *(uint2*)(Pe + (size_t)grow * 384 + (colbase - 384)) = o;
                }
            }
        }
    }
}

// ---------------------------------------------------------------------------
// CSR build
// ---------------------------------------------------------------------------
__global__ __launch_bounds__(256) void k_hist(const int* __restrict__ ei,
                                              int* __restrict__ deg, int E)
{
    int e = blockIdx.x * 256 + threadIdx.x;
    if (e < E) atomicAdd(&deg[ei[E + e]], 1);
}

__global__ __launch_bounds__(256) void k_scan1(const int* __restrict__ deg,
                                               int* __restrict__ rs,
                                               int* __restrict__ cs, int n)
{
    __shared__ int sh[256];
    int base = blockIdx.x * 1024;
    int t = threadIdx.x;
    int idx = base + t * 4;
    int v[4];
#pragma unroll
    for (int k = 0; k < 4; ++k) v[k] = (idx + k < n) ? deg[idx + k] : 0;
    int sum = v[0] + v[1] + v[2] + v[3];
    sh[t] = sum;
    __syncthreads();
    for (int off = 1; off < 256; off <<= 1) {
        int add = (t >= off) ? sh[t - off] : 0;
        __syncthreads();
        sh[t] += add;
        __syncthreads();
    }
    int run = sh[t] - sum;
    if (t == 255) cs[blockIdx.x] = sh[255];
#pragma unroll
    for (int k = 0; k < 4; ++k) {
        if (idx + k < n) rs[idx + k] = run;
        run += v[k];
    }
}

__global__ void k_scan2(int* __restrict__ cs, int nc)
{
    __shared__ int sh[64];
    int t = threadIdx.x;
    sh[t] = (t < nc) ? cs[t] : 0;
    __syncthreads();
    if (t == 0) {
        int acc = 0;
        for (int i = 0; i < nc; ++i) { int v = sh[i]; sh[i] = acc; acc += v; }
    }
    __syncthreads();
    if (t < nc) cs[t] = sh[t];
}

__global__ __launch_bounds__(256) void k_scan3(int* __restrict__ rs,
                                               const int* __restrict__ cs,
                                               int* __restrict__ cur, int n, int E)
{
    int i = blockIdx.x * 256 + threadIdx.x;
    if (i < n) {
        int v = rs[i] + cs[i >> 10];
        rs[i] = v;
        cur[i] = v;
    } else if (i == n) {
        rs[n] = E;
    }
}

__global__ __launch_bounds__(256) void k_scatter(const int* __restrict__ ei,
                                                 int* __restrict__ cur,
                                                 int2* __restrict__ sj, int E)
{
    int e = blockIdx.x * 256 + threadIdx.x;
    if (e < E) {
        int d = ei[E + e];
        int pos = atomicAdd(&cur[d], 1);
        int2 v; v.x = ei[e]; v.y = e;
        sj[pos] = v;
    }
}

// ---------------------------------------------------------------------------
// K3: fused attention + epilogue. One wave per node, 4 nodes/block.
// R2-verified structure (best measured): 8x/4x/1x unrolled gather,
// interleaved bf16 KV (1 dwordx2/edge) + fp32 ea (nontemporal), Pe bf16
// epilogue panel, cooperative S@We MFMA epilogue. UNCHANGED from R7 (passed).
// Failed experiments (do not retry without new evidence):
//  - degree-sorted perm (R3): 64-bin atomics cost +225us; zero gather gain
//  - per-wave MFMA epilogue (R4): +33us, serial vmcnt on B-frags
//  - register SW-pipeline (R5): +55us, VGPR 68 -> occupancy 32%
//  - two-edges-per-wave (R6): absmax 0.0625 > 0.0534 (FP reorder)
// ---------------------------------------------------------------------------
__global__ __launch_bounds__(256) void k_attn_fused(
    const float* __restrict__ Pq, const unsigned short* __restrict__ Pe,
    const unsigned int* __restrict__ KVb,
    const float* __restrict__ ea, const unsigned short* __restrict__ WeTb,
    const int* __restrict__ rs, const int2* __restrict__ sj,
    const float* __restrict__ ln_g, const float* __restrict__ ln_b,
    float* __restrict__ out)
{
    __shared__ unsigned short Sb_l[4 * 64];      // [node][k] bf16
    __shared__ float att_l[4 * 128];             // S@We result

    int tid = threadIdx.x;
    int wave = tid >> 6, lane = tid & 63;
    int node = blockIdx.x * 4 + wave;            // grid is exactly NN/4

    const float* Qrow = Pq + (size_t)node * 128;
    const unsigned short* Erow = Pe + (size_t)node * 384;
    float q0 = Qrow[lane];
    float q1 = Qrow[64 + lane];
    float wq = bfu(Erow[256 + lane]);

    float accd = 0.f, t0 = 0.f, t1 = 0.f, sA = 0.f;
    int beg = rs[node], end = rs[node + 1];

    int p = beg;
    for (; p + 8 <= end; p += 8) {
        float pp[8], aa[8], v0[8], v1[8];
#pragma unroll
        for (int u = 0; u < 8; ++u) {
            long long sv = __builtin_nontemporal_load((const long long*)(sj + p + u));
            int sx = (int)sv, sy = (int)(sv >> 32);
            uint2 kv2 = *(const uint2*)(KVb + (size_t)sx * 128 + 2 * lane);
            float a = __builtin_nontemporal_load(ea + (size_t)sy * 64 + lane);
            float k0 = __uint_as_float(kv2.x << 16);
            float k1 = __uint_as_float(kv2.x & 0xffff0000u);
            v0[u] = __uint_as_float(kv2.y << 16);
            v1[u] = __uint_as_float(kv2.y & 0xffff0000u);
            aa[u] = a;
            pp[u] = q0 * k0 + q1 * k1 + wq * a;
        }
#pragma unroll
        for (int o = 32; o > 0; o >>= 1) {
#pragma unroll
            for (int u = 0; u < 8; ++u) pp[u] += __shfl_xor(pp[u], o);
        }
#pragma unroll
        for (int u = 0; u < 8; ++u) {
            float ex = __expf(pp[u] * ASCALE);
            accd += ex;
            t0 += ex * v0[u];
            t1 += ex * v1[u];
            sA += ex * aa[u];
        }
    }
    for (; p + 4 <= end; p += 4) {
        float pp[4], aa[4], v0[4], v1[4];
#pragma unroll
        for (int u = 0; u < 4; ++u) {
            long long sv = __builtin_nontemporal_load((const long long*)(sj + p + u));
            int sx = (int)sv, sy = (int)(sv >> 32);
            uint2 kv2 = *(const uint2*)(KVb + (size_t)sx * 128 + 2 * lane);
            float a = __builtin_nontemporal_load(ea + (size_t)sy * 64 + lane);
            float k0 = __uint_as_float(kv2.x << 16);
            float k1 = __uint_as_float(kv2.x & 0xffff0000u);
            v0[u] = __uint_as_float(kv2.y << 16);
            v1[u] = __uint_as_float(kv2.y & 0xffff0000u);
            aa[u] = a;
            pp[u] = q0 * k0 + q1 * k1 + wq * a;
        }
#pragma unroll
        for (int o = 32; o > 0; o >>= 1) {
#pragma unroll
            for (int u = 0; u < 4; ++u) pp[u] += __shfl_xor(pp[u], o);
        }
#pragma unroll
        for (int u = 0; u < 4; ++u) {
            float ex = __expf(pp[u] * ASCALE);
            accd += ex;
            t0 += ex * v0[u];
            t1 += ex * v1[u];
            sA += ex * aa[u];
        }
    }
    for (; p < end; ++p) {
        long long sv = __builtin_nontemporal_load((const long long*)(sj + p));
        int sx = (int)sv, sy = (int)(sv >> 32);
        uint2 kv2 = *(const uint2*)(KVb + (size_t)sx * 128 + 2 * lane);
        float a = __builtin_nontemporal_load(ea + (size_t)sy * 64 + lane);
        float k0 = __uint_as_float(kv2.x << 16);
        float k1 = __uint_as_float(kv2.x & 0xffff0000u);
        float vv0 = __uint_as_float(kv2.y << 16);
        float vv1 = __uint_as_float(kv2.y & 0xffff0000u);
        float part = q0 * k0 + q1 * k1 + wq * a;
#pragma unroll
        for (int o = 32; o > 0; o >>= 1) part += __shfl_xor(part, o);
        float ex = __expf(part * ASCALE);
        accd += ex;
        t0 += ex * vv0;
        t1 += ex * vv1;
        sA += ex * a;
    }

    // accd is already lane-uniform (ex came from all-reduced alpha).

    // stage S (bf16) for MFMA
    Sb_l[wave * 64 + lane] = f2bf(sA);
    __syncthreads();   // orders Sb writes (all 4 waves) before MFMA reads

    // S@We: each wave computes 2 col-tiles of 16 for all 4 nodes.
    // B-fragments come straight from global (18KB table, L2/L1-hot).
    {
        int quad = lane >> 4, l16 = lane & 15;
        int arow = l16 & 3;     // A rows 4-15 duplicate rows 0-3; D rows 4-15 unused
        bf16x8 a0 = *(const bf16x8*)&Sb_l[arow * 64 + quad * 8];
        bf16x8 a1 = *(const bf16x8*)&Sb_l[arow * 64 + 32 + quad * 8];
#pragma unroll
        for (int c2 = 0; c2 < 2; ++c2) {
            int cn = wave * 2 + c2;
            int r = cn * 16 + l16;
            bf16x8 b0 = *(const bf16x8*)(WeTb + r * 72 + quad * 8);
            bf16x8 b1 = *(const bf16x8*)(WeTb + r * 72 + 32 + quad * 8);
            f32x4 acc = {};
            acc = __builtin_amdgcn_mfma_f32_16x16x32_bf16(a0, b0, acc, 0, 0, 0);
            acc = __builtin_amdgcn_mfma_f32_16x16x32_bf16(a1, b1, acc, 0, 0, 0);
            if (quad == 0) {
#pragma unroll
                for (int i = 0; i < 4; ++i)
                    att_l[i * 128 + cn * 16 + l16] = acc[i];
            }
        }
    }
    __syncthreads();

    float rcp = accd > 0.f ? 1.f / accd : 0.f;
    float a0f = (t0 + att_l[wave * 128 + lane]) * rcp + bfu(Erow[lane]);
    float a1f = (t1 + att_l[wave * 128 + 64 + lane]) * rcp + bfu(Erow[64 + lane]);

    float s = a0f + a1f;
#pragma unroll
    for (int o = 32; o > 0; o >>= 1) s += __shfl_xor(s, o);
    float mean = s * (1.f / 128.f);
    float d0 = a0f - mean, d1 = a1f - mean;
    float vs = d0 * d0 + d1 * d1;
#pragma unroll
    for (int o = 32; o > 0; o >>= 1) vs += __shfl_xor(vs, o);
    float inv = rsqrtf(vs * (1.f / 128.f) + 1e-5f);
    float n0 = d0 * inv * ln_g[lane] + ln_b[lane];
    float n1 = d1 * inv * ln_g[64 + lane] + ln_b[64 + lane];
    n0 = fmaxf(n0, 0.f);
    n1 = fmaxf(n1, 0.f);

    float g = bfu(Erow[320]);
    float r0 = bfu(Erow[128 + lane]);
    float r1 = bfu(Erow[192 + lane]);
    out[(size_t)node * 128 + lane] = g * n0 + (1.f - g) * r0;
    out[(size_t)node * 128 + 64 + lane] = g * n1 + (1.f - g) * r1;
}

// ---------------------------------------------------------------------------
extern "C" void kernel_launch(void* const* d_in, const int* in_sizes, int n_in,
                              void* d_out, int out_size, void* d_ws, size_t ws_size,
                              hipStream_t stream)
{
    const float* x     = (const float*)d_in[0];
    const int*   ei    = (const int*)d_in[1];
    const float* ea    = (const float*)d_in[2];
    const float* Wq    = (const float*)d_in[3];
    const float* bq    = (const float*)d_in[4];
    const float* Wk    = (const float*)d_in[5];
    const float* bk    = (const float*)d_in[6];
    const float* Wv    = (const float*)d_in[7];
    const float* bv    = (const float*)d_in[8];
    const float* We    = (const float*)d_in[9];
    const float* Wskip = (const float*)d_in[10];
    const float* bskip = (const float*)d_in[11];
    const float* ln_g  = (const float*)d_in[12];
    const float* ln_b  = (const float*)d_in[13];
    const float* Wres  = (const float*)d_in[14];
    const float* bres  = (const float*)d_in[15];
    const float* Wgate = (const float*)d_in[16];
    const float* bgate = (const float*)d_in[17];
    float* out = (float*)d_out;

    float* W = (float*)d_ws;
    size_t o = 0;
    auto falloc = [&](size_t e) { size_t r = o; o += e; return r; };
    size_t oPQ   = falloc((size_t)NN * 128);      // fp32 Q
    size_t oWQE  = falloc(8192);
    size_t oBQE  = falloc(64);
    size_t oBIAS = falloc(PC);
    size_t oKVB  = falloc((size_t)NN * 128);      // uint-sized (bf16 KV pairs)

    short* SB = (short*)(W + o);
    size_t oXB  = 0;                               // [NPAD*128] bf16
    size_t oWT  = oXB + (size_t)NPAD * 128;        // [768*128]  bf16
    size_t oWET = oWT + (size_t)PC * 128;          // [128*72]   bf16
    size_t oPE  = oWET + 128 * 72;                 // [NN*384]   bf16 epilogue panel
    size_t sh_total = oPE + (size_t)NN * 384;

    int* IB = (int*)(SB + ((sh_total + 1) & ~(size_t)1));
    size_t io = 0;
    auto ialloc = [&](size_t e) { size_t r = io; io += e; return r; };
    size_t oSJ   = ialloc((size_t)2 * EE);         // int2, 8B-aligned at IB+0
    size_t oDEG  = ialloc(NN);
    size_t oRS   = ialloc(NN + 1);
    size_t oCUR  = ialloc(NN);
    size_t oCS   = ialloc(64);

    hipMemsetAsync(IB + oDEG, 0, NN * sizeof(int), stream);

    k_prep<<<NXB + 33, 256, 0, stream>>>(x, SB + oXB, Wq, bq, We,
                                         W + oWQE, W + oBQE);
    k_packw<<<(PC * 128 + PC + 128 * 72 + 255) / 256, 256, 0, stream>>>(
        Wq, bq, Wk, bk, Wv, bv, Wskip, bskip, Wres, bres, Wgate, bgate,
        W + oWQE, W + oBQE, We, SB + oWT, W + oBIAS,
        (unsigned short*)(SB + oWET));

    dim3 ggrid(PC / 64, NPAD / 128);   // bn fastest -> A-tile L2 reuse
    k_gemm<<<ggrid, 256, 0, stream>>>(SB + oXB, SB + oWT, W + oBIAS, W + oPQ,
                                      (unsigned short*)(SB + oPE),
                                      (unsigned short*)(W + oKVB));

    k_hist<<<(EE + 255) / 256, 256, 0, stream>>>(ei, IB + oDEG, EE);
    k_scan1<<<49, 256, 0, stream>>>(IB + oDEG, IB + oRS, IB + oCS, NN);
    k_scan2<<<1, 64, 0, stream>>>(IB + oCS, 49);
    k_scan3<<<(NN + 256) / 256, 256, 0, stream>>>(IB + oRS, IB + oCS, IB + oCUR, NN, EE);
    k_scatter<<<(EE + 255) / 256, 256, 0, stream>>>(ei, IB + oCUR, (int2*)(IB + oSJ), EE);

    k_attn_fused<<<NN / 4, 256, 0, stream>>>(
        W + oPQ, (const unsigned short*)(SB + oPE),
        (const unsigned int*)(W + oKVB), ea,
        (const unsigned short*)(SB + oWET),
        IB + oRS, (const int2*)(IB + oSJ), ln_g, ln_b, out);
}